// Round 3
// baseline (5587.771 us; speedup 1.0000x reference)
//
#include <hip/hip_runtime.h>
#include <hip/hip_bf16.h>
#include <cstdint>
#include <cstddef>

// ---------------------------------------------------------------------------
// MMPrompt pipeline, round 3: bf16 MFMA GEMMs with conflict-free LDS staging
// (strided B ownership), packed f32->bf16 conversion, fused elementwise.
// ---------------------------------------------------------------------------

namespace {

constexpr int NE   = 30000;
constexpr int NM   = 6000;
constexpr int Dm   = 384;
constexpr int Hm   = 768;
constexpr int NREL = 12;
constexpr int EKG  = 200000;
constexpr int EC   = 200000;
constexpr int ES   = 80000;
constexpr int Bc   = 16;
constexpr int LE   = 48;
constexpr int LT   = 256;
constexpr int NTOK = Bc * LT;     // 4096
constexpr int NO   = 18432;

constexpr size_t NBf = (size_t)NE * Dm;   // 11,520,000
constexpr size_t MBF = (size_t)NM * Dm;   // 2,304,000

// ---- phase 1 overlay (graph work) ----
constexpr size_t OFF_AGG  = 0;
constexpr size_t OFF_ENT0 = NBf;
constexpr size_t OFF_ACC  = 2 * NBf;
constexpr size_t OFF_CCUR = 3 * NBf;
constexpr size_t OFF_NF   = 4 * NBf;
constexpr size_t OFF_G1   = OFF_NF + MBF;
constexpr size_t OFF_G2   = OFF_G1 + MBF;
constexpr size_t OFF_G3   = OFF_G2 + MBF;
constexpr size_t OFF_G4   = OFF_G3 + MBF;
constexpr size_t OFF_CNT  = OFF_G4 + MBF;
constexpr size_t OFF_WCAT = OFF_CNT + (size_t)NREL * NE;
constexpr size_t OFF_ENT  = OFF_WCAT + (size_t)NREL * Dm * Dm;
constexpr size_t OFF_EEMB = OFF_ENT + NBf;
constexpr size_t OFF_DISC = OFF_EEMB + (size_t)Bc * LE * Hm;
constexpr size_t OFF_DIST = OFF_DISC + NE;
constexpr size_t OFF_DISI = OFF_DIST + NM;
constexpr size_t OFF_END  = OFF_DISI + NM;

// ---- phase 2 overlay ----
constexpr size_t OFF_HID  = 0;
constexpr size_t OFF_ENT2 = (size_t)NE * 192;
constexpr size_t OFF_E768 = OFF_ENT2 + NBf;
constexpr size_t OFF_THID = OFF_E768 + (size_t)NE * Hm;
constexpr size_t OFF_TOK  = OFF_THID + (size_t)NTOK * Dm;
constexpr size_t OFF_TOK2 = OFF_TOK + (size_t)NTOK * Hm;
constexpr size_t OFF_Q    = OFF_TOK2 + (size_t)NTOK * Hm;
constexpr size_t OFF_PR0  = OFF_Q + (size_t)NTOK * Hm;
constexpr size_t OFF_PHID = OFF_PR0 + (size_t)NTOK * Hm;
constexpr size_t OFF_P2E  = OFF_PHID + (size_t)NTOK * Dm;

static_assert(OFF_END <= 75497472ull, "d_out overlay overflow");
static_assert(OFF_P2E <= OFF_ENT, "phase2 overlay collides with ENT");

inline int cdiv(long a, long b) { return (int)((a + b - 1) / b); }

} // namespace

typedef short short8v __attribute__((ext_vector_type(8)));
typedef float f32x4 __attribute__((ext_vector_type(4)));

__device__ __forceinline__ uint32_t pkbf(float a, float b) {
  __hip_bfloat162 h = __float22bfloat162_rn(float2{a, b});
  union { __hip_bfloat162 h; uint32_t u; } cv;
  cv.h = h;
  return cv.u;
}

// ---------------------------------------------------------------------------
// small kernels
// ---------------------------------------------------------------------------

__global__ void k_count_type(const int* __restrict__ dst, const int* __restrict__ typ,
                             float* __restrict__ cnt, int E) {
  int i = blockIdx.x * 256 + threadIdx.x;
  if (i < E) atomicAdd(&cnt[(size_t)typ[i] * NE + dst[i]], 1.0f);
}

__global__ void k_deg(const int* __restrict__ dst, float* __restrict__ deg, int E) {
  int i = blockIdx.x * 256 + threadIdx.x;
  if (i < E) atomicAdd(&deg[dst[i]], 1.0f);
}

__global__ void k_dis(float* __restrict__ d, int n) {
  int i = blockIdx.x * 256 + threadIdx.x;
  if (i < n) d[i] = rsqrtf(d[i] + 1.0f);
}

__global__ void k_wcat(const float* __restrict__ comp, const float* __restrict__ bases,
                       float* __restrict__ Wc) {
  int idx = blockIdx.x * 256 + threadIdx.x;
  if (idx >= NREL * Dm * Dm) return;
  int r = idx / (Dm * Dm);
  int io = idx - r * (Dm * Dm);
  float s = 0.f;
#pragma unroll
  for (int b = 0; b < 8; ++b) s += comp[r * 8 + b] * bases[(size_t)b * Dm * Dm + io];
  Wc[idx] = s;
}

__global__ void k_scatter_rgcn(const int* __restrict__ ei, const int* __restrict__ typ,
                               const float* __restrict__ cnt, const float* __restrict__ x,
                               float* __restrict__ agg, int E, int r) {
  int w = (int)((blockIdx.x * (size_t)blockDim.x + threadIdx.x) >> 6);
  int lane = threadIdx.x & 63;
  if (w >= E) return;
  if (typ[w] != r) return;
  int s = ei[w], d = ei[E + w];
  float c = 1.0f / cnt[(size_t)r * NE + d];
  const float* xs = x + (size_t)s * Dm;
  float* od = agg + (size_t)d * Dm;
#pragma unroll
  for (int i = 0; i < Dm / 64; ++i)
    atomicAdd(&od[lane + 64 * i], c * xs[lane + 64 * i]);
}

__global__ void k_gcn_init(const float* __restrict__ x, const float* __restrict__ dis,
                           float* __restrict__ out, int n) {
  size_t i = (size_t)blockIdx.x * 256 + threadIdx.x;
  if (i >= (size_t)n * Dm) return;
  int row = (int)(i / Dm);
  float d = dis[row];
  out[i] = d * d * x[i];
}

__global__ void k_gcn_scatter(const int* __restrict__ ei, const float* __restrict__ dis,
                              const float* __restrict__ x, float* __restrict__ out, int E) {
  int w = (int)((blockIdx.x * (size_t)blockDim.x + threadIdx.x) >> 6);
  int lane = threadIdx.x & 63;
  if (w >= E) return;
  int s = ei[w], d = ei[E + w];
  float c = dis[s] * dis[d];
  const float* xs = x + (size_t)s * Dm;
  float* od = out + (size_t)d * Dm;
#pragma unroll
  for (int i = 0; i < Dm / 64; ++i)
    atomicAdd(&od[lane + 64 * i], c * xs[lane + 64 * i]);
}

// ent = 0.25*(a+b+c+d)
__global__ void k_combine4(const float* __restrict__ a, const float* __restrict__ b,
                           const float* __restrict__ c, const float* __restrict__ d,
                           float* __restrict__ out, size_t n) {
  size_t i = (size_t)blockIdx.x * 256 + threadIdx.x;
  if (i < n) out[i] = 0.25f * (a[i] + b[i] + c[i] + d[i]);
}

__global__ void k_gather(const int* __restrict__ idx, const float* __restrict__ x,
                         float* __restrict__ out, int rows, int D) {
  size_t i = (size_t)blockIdx.x * 256 + threadIdx.x;
  if (i >= (size_t)rows * D) return;
  int r = (int)(i / D);
  int d = (int)(i - (size_t)r * D);
  out[i] = x[(size_t)idx[r] * D + d];
}

// ent[mte[m]] += 0.25*(g1+g2+g3+g4)
__global__ void k_scatter_movie4(const int* __restrict__ mte,
                                 const float* __restrict__ g1, const float* __restrict__ g2,
                                 const float* __restrict__ g3, const float* __restrict__ g4,
                                 float* __restrict__ ent) {
  size_t i = (size_t)blockIdx.x * 256 + threadIdx.x;
  if (i >= MBF) return;
  int m = (int)(i / Dm);
  int d = (int)(i - (size_t)m * Dm);
  float v = 0.25f * (g1[i] + g2[i] + g3[i] + g4[i]);
  atomicAdd(&ent[(size_t)mte[m] * Dm + d], v);
}

// ---------------------------------------------------------------------------
// bf16 MFMA GEMM, 128x128 tile, BK=64, 4 waves (2x2), 64x64 per wave.
// LDS: row-major [128 rows][64 k-shorts], 8-short slots XOR-swizzled by row&7.
// A staged per-thread as (row, 32 contig k); B staged as strided rows
// r = (tid&15)*2 + q + 32h so simultaneous ds_writes spread across slots
// (conflict-free; the round-2 layout was a 16-way write conflict).
// Requires K % 64 == 0, N % 32 == 0.
// ---------------------------------------------------------------------------
template <bool RELU, bool ACCUM, bool RES, bool FINAL>
__global__ __launch_bounds__(256) void mgemm(
    const float* __restrict__ A, const float* __restrict__ W,
    const float* __restrict__ bias, const float* __restrict__ Rp,
    float* __restrict__ C, int M, int N, int K) {
  __shared__ __align__(16) short As[128 * 64];
  __shared__ __align__(16) short Bs[128 * 64];
  const int tid = threadIdx.x;
  const int bm = blockIdx.x * 128, bn = blockIdx.y * 128;
  const int lane = tid & 63;
  const int w = tid >> 6;
  const int wr = (w >> 1) * 64, wc = (w & 1) * 64;
  const int lrow = lane & 15;
  const int lq = lane >> 4;

  f32x4 acc[4][4] = {};

  // A staging: thread -> (row = tid>>1, 32 contiguous k at (tid&1)*32)
  const int s_row = tid >> 1;
  const int s_kh = (tid & 1) * 32;
  const bool a_ok = (bm + s_row) < M;
  const float* Ap = A + (size_t)(bm + s_row) * K + s_kh;

  // B staging: thread -> k-rows [b_kq*4, +4), cols (t4*2 + q) + 32*h
  const int b_kq = tid >> 4;   // 0..15
  const int t4 = tid & 15;
  const float* Wp = W + (size_t)(b_kq * 4) * N + bn + t4 * 2;
  bool h_ok[4];
#pragma unroll
  for (int h = 0; h < 4; ++h) h_ok[h] = (bn + 32 * h) < N;

  for (int k0 = 0; k0 < K; k0 += 64) {
    float4 av[8];
    if (a_ok) {
      const float4* p = (const float4*)(Ap + k0);
#pragma unroll
      for (int i = 0; i < 8; ++i) av[i] = p[i];
    } else {
#pragma unroll
      for (int i = 0; i < 8; ++i) av[i] = float4{0.f, 0.f, 0.f, 0.f};
    }
    float2 bv[4][4];   // [kk][h]
#pragma unroll
    for (int kk = 0; kk < 4; ++kk) {
      const float* rowp = Wp + (size_t)(k0 + kk) * N;
#pragma unroll
      for (int h = 0; h < 4; ++h)
        bv[kk][h] = h_ok[h] ? *(const float2*)(rowp + 32 * h) : float2{0.f, 0.f};
    }
    __syncthreads();   // previous tile's reads done
#pragma unroll
    for (int j = 0; j < 4; ++j) {
      uint32_t p0 = pkbf(av[2 * j].x, av[2 * j].y);
      uint32_t p1 = pkbf(av[2 * j].z, av[2 * j].w);
      uint32_t p2 = pkbf(av[2 * j + 1].x, av[2 * j + 1].y);
      uint32_t p3 = pkbf(av[2 * j + 1].z, av[2 * j + 1].w);
      int kk = s_kh + j * 8;
      int off = s_row * 64 + (((kk >> 3) ^ (s_row & 7)) << 3);
      *(uint4*)&As[off] = uint4{p0, p1, p2, p3};
    }
#pragma unroll
    for (int h = 0; h < 4; ++h) {
#pragma unroll
      for (int q = 0; q < 2; ++q) {
        float e0 = q ? bv[0][h].y : bv[0][h].x;
        float e1 = q ? bv[1][h].y : bv[1][h].x;
        float e2 = q ? bv[2][h].y : bv[2][h].x;
        float e3 = q ? bv[3][h].y : bv[3][h].x;
        uint32_t p0 = pkbf(e0, e1);
        uint32_t p1 = pkbf(e2, e3);
        int r = t4 * 2 + q + 32 * h;
        int off = r * 64 + (((b_kq >> 1) ^ (r & 7)) << 3) + (b_kq & 1) * 4;
        *(uint2*)&Bs[off] = uint2{p0, p1};
      }
    }
    __syncthreads();
#pragma unroll
    for (int ks = 0; ks < 2; ++ks) {
      short8v af[4], bf[4];
      const int slot = ks * 4 + lq;
#pragma unroll
      for (int mr = 0; mr < 4; ++mr) {
        int r = wr + mr * 16 + lrow;
        af[mr] = *(const short8v*)&As[r * 64 + ((slot ^ (r & 7)) << 3)];
      }
#pragma unroll
      for (int nc = 0; nc < 4; ++nc) {
        int r = wc + nc * 16 + lrow;
        bf[nc] = *(const short8v*)&Bs[r * 64 + ((slot ^ (r & 7)) << 3)];
      }
#pragma unroll
      for (int mr = 0; mr < 4; ++mr)
#pragma unroll
        for (int nc = 0; nc < 4; ++nc)
          acc[mr][nc] = __builtin_amdgcn_mfma_f32_16x16x32_bf16(
              af[mr], bf[nc], acc[mr][nc], 0, 0, 0);
    }
  }
  // epilogue: D frag: col = lane&15, row = (lane>>4)*4 + e
#pragma unroll
  for (int mr = 0; mr < 4; ++mr) {
#pragma unroll
    for (int e = 0; e < 4; ++e) {
      int r = bm + wr + mr * 16 + lq * 4 + e;
      if (r >= M) continue;
#pragma unroll
      for (int nc = 0; nc < 4; ++nc) {
        int c = bn + wc + nc * 16 + lrow;
        if (c >= N) continue;
        float v = acc[mr][nc][e];
        if (bias) v += bias[c];
        if (RES) v += Rp[(size_t)r * N + c];
        if (RELU) v = fmaxf(v, 0.f);
        if (FINAL) {
          int b = r >> 8, t = r & 255;
          int l = c / 1536, rem = c - l * 1536;
          int blk = rem / 768, rem2 = rem - blk * 768;
          int hh = rem2 >> 6, dd = rem2 & 63;
          size_t oi = (((((size_t)l * 2 + blk) * 16 + b) * 12 + hh) * 256 + t) * 64 + dd;
          C[oi] = v;
        } else if (ACCUM) {
          C[(size_t)r * N + c] += v;
        } else {
          C[(size_t)r * N + c] = v;
        }
      }
    }
  }
}

// fused cross-attention: one wave per (b,t)
__global__ __launch_bounds__(256) void k_attn(const float* __restrict__ q,
                                              const float* __restrict__ eemb,
                                              const float* __restrict__ tok,
                                              float* __restrict__ out) {
  int gw = (int)((blockIdx.x * (size_t)blockDim.x + threadIdx.x) >> 6);
  int lane = threadIdx.x & 63;
  if (gw >= NTOK) return;
  int b = gw >> 8;
  const float* qr = q + (size_t)gw * Hm;
  float qreg[12];
#pragma unroll
  for (int i = 0; i < 12; ++i) qreg[i] = qr[lane + 64 * i];
  const float* eb = eemb + (size_t)b * LE * Hm;
  float myA = -3.0e38f;
  for (int e = 0; e < LE; ++e) {
    const float* er = eb + (size_t)e * Hm;
    float s = 0.f;
#pragma unroll
    for (int i = 0; i < 12; ++i) s = fmaf(qreg[i], er[lane + 64 * i], s);
#pragma unroll
    for (int off = 32; off > 0; off >>= 1) s += __shfl_xor(s, off);
    if (lane == e) myA = s * (1.0f / 768.0f);
  }
  float mx = myA;
#pragma unroll
  for (int off = 32; off > 0; off >>= 1) mx = fmaxf(mx, __shfl_xor(mx, off));
  float p = (lane < LE) ? expf(myA - mx) : 0.f;
  float sum = p;
#pragma unroll
  for (int off = 32; off > 0; off >>= 1) sum += __shfl_xor(sum, off);
  float w = p / sum;
  const float* tr = tok + (size_t)gw * Hm;
  float acc[12];
#pragma unroll
  for (int i = 0; i < 12; ++i) acc[i] = tr[lane + 64 * i];
  for (int e = 0; e < LE; ++e) {
    float we = __shfl(w, e);
    const float* er = eb + (size_t)e * Hm;
#pragma unroll
    for (int i = 0; i < 12; ++i) acc[i] = fmaf(we, er[lane + 64 * i], acc[i]);
  }
  float* orow = out + (size_t)gw * Hm;
#pragma unroll
  for (int i = 0; i < 12; ++i) orow[lane + 64 * i] = acc[i];
}

// ---------------------------------------------------------------------------

extern "C" void kernel_launch(void* const* d_in, const int* in_sizes, int n_in,
                              void* d_out, int out_size, void* d_ws, size_t ws_size,
                              hipStream_t stream) {
  (void)in_sizes; (void)n_in; (void)out_size; (void)ws_size;

  const float* x_node = (const float*)d_in[0];
  const float* bases  = (const float*)d_in[1];
  const float* comp   = (const float*)d_in[2];
  const float* root   = (const float*)d_in[3];
  const float* rbias  = (const float*)d_in[4];
  const float* ep1w1  = (const float*)d_in[5];
  const float* ep1b1  = (const float*)d_in[6];
  const float* ep1w2  = (const float*)d_in[7];
  const float* ep1b2  = (const float*)d_in[8];
  const float* ep2w   = (const float*)d_in[9];
  const float* ep2b   = (const float*)d_in[10];
  const float* tp1w1  = (const float*)d_in[11];
  const float* tp1b1  = (const float*)d_in[12];
  const float* tp1w2  = (const float*)d_in[13];
  const float* tp1b2  = (const float*)d_in[14];
  const float* tp2w   = (const float*)d_in[15];
  const float* tp2b   = (const float*)d_in[16];
  const float* caw    = (const float*)d_in[17];
  const float* pp1w1  = (const float*)d_in[18];
  const float* pp1b1  = (const float*)d_in[19];
  const float* pp1w2  = (const float*)d_in[20];
  const float* pp1b2  = (const float*)d_in[21];
  const float* pp2w   = (const float*)d_in[22];
  const float* pp2b   = (const float*)d_in[23];
  const float* tokens = (const float*)d_in[24];
  const int* ei_kg = (const int*)d_in[25];
  const int* etype = (const int*)d_in[26];
  const int* ei_c  = (const int*)d_in[27];
  const int* ei_ts = (const int*)d_in[28];
  const int* ei_is = (const int*)d_in[29];
  const int* mte   = (const int*)d_in[30];
  const int* eids  = (const int*)d_in[31];

  float* O = (float*)d_out;
  float* f_agg  = O + OFF_AGG;
  float* f_ent0 = O + OFF_ENT0;
  float* f_acc  = O + OFF_ACC;
  float* f_ccur = O + OFF_CCUR;
  float* f_nf   = O + OFF_NF;
  float* f_g1   = O + OFF_G1;
  float* f_g2   = O + OFF_G2;
  float* f_g3   = O + OFF_G3;
  float* f_g4   = O + OFF_G4;
  float* f_cnt  = O + OFF_CNT;
  float* f_wcat = O + OFF_WCAT;
  float* f_ent  = O + OFF_ENT;
  float* f_eemb = O + OFF_EEMB;
  float* f_disc = O + OFF_DISC;
  float* f_dist = O + OFF_DIST;
  float* f_disi = O + OFF_DISI;
  float* f_hid  = O + OFF_HID;
  float* f_ent2 = O + OFF_ENT2;
  float* f_e768 = O + OFF_E768;
  float* f_thid = O + OFF_THID;
  float* f_tok  = O + OFF_TOK;
  float* f_tok2 = O + OFF_TOK2;
  float* f_q    = O + OFF_Q;
  float* f_pr0  = O + OFF_PR0;
  float* f_phid = O + OFF_PHID;
  float* f_p2   = (float*)d_ws;

  const int EW = 256;

  // ---------------- RGCN ----------------
  hipMemsetAsync(f_cnt, 0, (size_t)NREL * NE * 4, stream);
  k_count_type<<<cdiv(EKG, EW), EW, 0, stream>>>(ei_kg + EKG, etype, f_cnt, EKG);
  k_wcat<<<cdiv(NREL * Dm * Dm, EW), EW, 0, stream>>>(comp, bases, f_wcat);
  // ent0 = x @ root + bias + x   (residual folded in)
  mgemm<false, false, true, false><<<dim3(cdiv(NE, 128), cdiv(Dm, 128)), 256, 0, stream>>>(
      x_node, root, rbias, x_node, f_ent0, NE, Dm, Dm);
  for (int r = 0; r < NREL; ++r) {
    hipMemsetAsync(f_agg, 0, NBf * 4, stream);
    k_scatter_rgcn<<<cdiv((long)EKG * 64, EW), EW, 0, stream>>>(
        ei_kg, etype, f_cnt, x_node, f_agg, EKG, r);
    mgemm<false, true, false, false><<<dim3(cdiv(NE, 128), cdiv(Dm, 128)), 256, 0, stream>>>(
        f_agg, f_wcat + (size_t)r * Dm * Dm, nullptr, nullptr, f_ent0, NE, Dm, Dm);
  }

  // ---------------- degree norms ----------------
  hipMemsetAsync(f_disc, 0, NE * 4, stream);
  k_deg<<<cdiv(EC, EW), EW, 0, stream>>>(ei_c + EC, f_disc, EC);
  k_dis<<<cdiv(NE, EW), EW, 0, stream>>>(f_disc, NE);
  hipMemsetAsync(f_dist, 0, NM * 4, stream);
  k_deg<<<cdiv(ES, EW), EW, 0, stream>>>(ei_ts + ES, f_dist, ES);
  k_dis<<<cdiv(NM, EW), EW, 0, stream>>>(f_dist, NM);
  hipMemsetAsync(f_disi, 0, NM * 4, stream);
  k_deg<<<cdiv(ES, EW), EW, 0, stream>>>(ei_is + ES, f_disi, ES);
  k_dis<<<cdiv(NM, EW), EW, 0, stream>>>(f_disi, NM);

  // ---------------- movie branch: ts1->G1 ts2->G2 is1->G3 is2->G4 --------
  k_gather<<<cdiv(MBF, EW), EW, 0, stream>>>(mte, f_ent0, f_nf, NM, Dm);
  k_gcn_init<<<cdiv(MBF, EW), EW, 0, stream>>>(f_nf, f_dist, f_g1, NM);
  k_gcn_scatter<<<cdiv((long)ES * 64, EW), EW, 0, stream>>>(ei_ts, f_dist, f_nf, f_g1, ES);
  k_gcn_init<<<cdiv(MBF, EW), EW, 0, stream>>>(f_g1, f_dist, f_g2, NM);
  k_gcn_scatter<<<cdiv((long)ES * 64, EW), EW, 0, stream>>>(ei_ts, f_dist, f_g1, f_g2, ES);
  k_gcn_init<<<cdiv(MBF, EW), EW, 0, stream>>>(f_nf, f_disi, f_g3, NM);
  k_gcn_scatter<<<cdiv((long)ES * 64, EW), EW, 0, stream>>>(ei_is, f_disi, f_nf, f_g3, ES);
  k_gcn_init<<<cdiv(MBF, EW), EW, 0, stream>>>(f_g3, f_disi, f_g4, NM);
  k_gcn_scatter<<<cdiv((long)ES * 64, EW), EW, 0, stream>>>(ei_is, f_disi, f_g3, f_g4, ES);

  // ---------------- entity GCN chain: c1->AGG c2->CCUR c3->ACC ------------
  k_gcn_init<<<cdiv(NBf, EW), EW, 0, stream>>>(f_ent0, f_disc, f_agg, NE);
  k_gcn_scatter<<<cdiv((long)EC * 64, EW), EW, 0, stream>>>(ei_c, f_disc, f_ent0, f_agg, EC);
  k_gcn_init<<<cdiv(NBf, EW), EW, 0, stream>>>(f_agg, f_disc, f_ccur, NE);
  k_gcn_scatter<<<cdiv((long)EC * 64, EW), EW, 0, stream>>>(ei_c, f_disc, f_agg, f_ccur, EC);
  k_gcn_init<<<cdiv(NBf, EW), EW, 0, stream>>>(f_ccur, f_disc, f_acc, NE);
  k_gcn_scatter<<<cdiv((long)EC * 64, EW), EW, 0, stream>>>(ei_c, f_disc, f_ccur, f_acc, EC);
  k_combine4<<<cdiv(NBf, EW), EW, 0, stream>>>(f_ent0, f_agg, f_ccur, f_acc, f_ent, NBf);
  k_scatter_movie4<<<cdiv(MBF, EW), EW, 0, stream>>>(mte, f_g1, f_g2, f_g3, f_g4, f_ent);

  // ---------------- entity MLP ----------------
  mgemm<true, false, false, false><<<dim3(cdiv(NE, 128), cdiv(192, 128)), 256, 0, stream>>>(
      f_ent, ep1w1, ep1b1, nullptr, f_hid, NE, 192, Dm);
  mgemm<false, false, true, false><<<dim3(cdiv(NE, 128), cdiv(Dm, 128)), 256, 0, stream>>>(
      f_hid, ep1w2, ep1b2, f_ent, f_ent2, NE, Dm, 192);
  mgemm<false, false, false, false><<<dim3(cdiv(NE, 128), cdiv(Hm, 128)), 256, 0, stream>>>(
      f_ent2, ep2w, ep2b, nullptr, f_e768, NE, Hm, Dm);

  // ---------------- token path ----------------
  mgemm<true, false, false, false><<<dim3(cdiv(NTOK, 128), cdiv(Dm, 128)), 256, 0, stream>>>(
      tokens, tp1w1, tp1b1, nullptr, f_thid, NTOK, Dm, Hm);
  mgemm<false, false, true, false><<<dim3(cdiv(NTOK, 128), cdiv(Hm, 128)), 256, 0, stream>>>(
      f_thid, tp1w2, tp1b2, tokens, f_tok, NTOK, Hm, Dm);
  mgemm<false, false, false, false><<<dim3(cdiv(NTOK, 128), cdiv(Hm, 128)), 256, 0, stream>>>(
      f_tok, tp2w, tp2b, nullptr, f_tok2, NTOK, Hm, Hm);
  mgemm<false, false, false, false><<<dim3(cdiv(NTOK, 128), cdiv(Hm, 128)), 256, 0, stream>>>(
      f_tok2, caw, nullptr, nullptr, f_q, NTOK, Hm, Hm);

  k_gather<<<cdiv((long)Bc * LE * Hm, EW), EW, 0, stream>>>(eids, f_e768, f_eemb, Bc * LE, Hm);
  k_attn<<<cdiv((long)NTOK * 64, 256), 256, 0, stream>>>(f_q, f_eemb, f_tok2, f_pr0);

  mgemm<true, false, false, false><<<dim3(cdiv(NTOK, 128), cdiv(Dm, 128)), 256, 0, stream>>>(
      f_pr0, pp1w1, pp1b1, nullptr, f_phid, NTOK, Dm, Hm);
  mgemm<false, false, true, false><<<dim3(cdiv(NTOK, 128), cdiv(Hm, 128)), 256, 0, stream>>>(
      f_phid, pp1w2, pp1b2, f_pr0, f_p2, NTOK, Hm, Dm);

  // ---------------- final GEMM + transpose ----------------
  mgemm<false, false, false, true><<<dim3(cdiv(NTOK, 128), cdiv(NO, 128)), 256, 0, stream>>>(
      f_p2, pp2w, pp2b, nullptr, O, NTOK, NO, Hm);
}

// Round 6
// 1791.929 us; speedup vs baseline: 3.1183x; 3.1183x over previous
//
#include <hip/hip_runtime.h>
#include <hip/hip_bf16.h>
#include <cstdint>
#include <cstddef>

// ---------------------------------------------------------------------------
// MMPrompt pipeline, round 6 (= round 5 + final-GEMM B operand moved OUT of
// d_out):
//  - THE round-5 bug: final GEMM read pp2t from d_out while writing all of
//    d_out -> race -> bf16-reinterpreted f32 low bits -> NaN. pp2t now lives
//    in d_ws (over the dead CSR arrays); if ws_size is too small we fall back
//    to an in-kernel-conversion final GEMM reading pp2w (d_in) directly.
//  - all GEMMs: bf16 operands, m97-style global_load_lds staging (16B),
//    XOR-swizzled LDS via pre-swizzled global addresses, MFMA 16x16x32.
//  - RGCN via 2 big GEMMs + CSR gathers; GCNs via CSR gathers (no atomics).
// ---------------------------------------------------------------------------

namespace {

constexpr int NE   = 30000;
constexpr int NM   = 6000;
constexpr int Dm   = 384;
constexpr int Hm   = 768;
constexpr int EKG  = 200000;
constexpr int EC   = 200000;
constexpr int ES   = 80000;
constexpr int Bc   = 16;
constexpr int LE   = 48;
constexpr int NTOK = 4096;
constexpr int NO   = 18432;

constexpr size_t NBf = (size_t)NE * Dm;   // 11,520,000
constexpr size_t MBF = (size_t)NM * Dm;   // 2,304,000

// ---------------- d_out arena (f32-unit offsets) ----------------
// phase A (conversions + RGCN)
constexpr size_t P_XB    = 0;          // xb bf16 NE*384           ends 5,760,000
constexpr size_t P_WCT   = 5760000;    // wcat_t bf16 12*384*384   ends 6,644,736
constexpr size_t P_CNT   = 6644736;    // rcp cnt f32 12*NE        ends 7,004,736
constexpr size_t P_ENT0  = 7004736;    // f32 NE*384               ends 18,524,736
constexpr size_t P_HH    = 18524736;   // h bf16 NE*2304           ends 53,084,736
constexpr size_t P_DIS   = 53084736;   // disc+dist+disi f32 42,000 ends 53,126,736
// phase B (graph chains) — xb/wct/rcpc dead
constexpr size_t P_NF    = 0;          // f32 NM*384   ends 2,304,000
constexpr size_t P_G1    = 2304000;    //              ends 4,608,000
constexpr size_t P_G2    = 4608000;    //              ends 6,912,000
constexpr size_t P_CPREV = 18524736;   // f32 NE*384 (over dead hh)
constexpr size_t P_CCUR  = 30044736;
constexpr size_t P_ACC   = 41564736;   // becomes ENT; ends 53,084,736
constexpr size_t P_G3    = 53200000;   // ends 55,504,000
constexpr size_t P_ENTB  = 55600000;   // bf16 NE*384  ends 61,360,000
// phase C (MLP/token/attn) — nf/g*/ent0/cprev/ccur dead
constexpr size_t P_HIDB  = 0;          // bf16 NE*192   ends 2,880,000
constexpr size_t P_ENT2B = 2880000;    // bf16 NE*384   ends 8,640,000
constexpr size_t P_E768B = 8640000;    // bf16 NE*768   ends 20,160,000
constexpr size_t P_TOKB  = 20160000;   // bf16 4096*768 ends 21,732,864 (phase-C write)
constexpr size_t P_THIDB = 21732864;   // bf16 4096*384 ends 22,519,296
constexpr size_t P_TOK1B = 22519296;   // bf16 4096*768
constexpr size_t P_TOK2B = 24092160;   // bf16 4096*768
constexpr size_t P_QB    = 25665024;   // bf16 4096*768
constexpr size_t P_EEMB  = 27237888;   // bf16 768*Hm    ends 27,532,800
constexpr size_t P_PR0   = 27532800;   // f32 4096*768   ends 30,678,528
constexpr size_t P_PR0B  = 30678528;   // bf16 4096*768  ends 32,251,392
constexpr size_t P_PHIDB = 32251392;   // bf16 4096*384  ends 33,037,824
// whole-launch small weights (dead before final GEMM runs? NO — but they are
// NOT read by the final GEMM; they are clobbered by its output, which is fine)
constexpr size_t P_WT    = 74000000;   // ends 75,474,560 < 75,497,472
// short-offsets within P_WT:
constexpr size_t S_ROOT  = 0;          // [384][384]
constexpr size_t S_EP1A  = 147456;     // [192][384]
constexpr size_t S_EP1B  = 221184;     // [384][192]
constexpr size_t S_EP2   = 294912;     // [768][384]
constexpr size_t S_TP1A  = 589824;     // [384][768]
constexpr size_t S_TP1B  = 884736;     // [768][384]
constexpr size_t S_TP2   = 1179648;    // [768][768]
constexpr size_t S_CAW   = 1769472;    // [768][768]
constexpr size_t S_PP1A  = 2359296;    // [384][768]
constexpr size_t S_PP1B  = 2654208;    // [768][384] ends 2,949,120 shorts

// ---------------- d_ws layout (bytes) ----------------
// [0, 6,291,456)            p2b  bf16 4096*768   (live until final GEMM done)
// [6,291,456, 9,228,480)    CSR int arrays       (dead after entity chain)
// [6,291,456, 34,603,008)   pp2t bf16 18432*768  (overlays CSR; written after
//                                                 entity chain, read by final)
constexpr size_t WI       = 6291456 / 4;
constexpr size_t I_CNT    = WI + 0;
constexpr size_t I_PART   = WI + 30000;
constexpr size_t I_KG_RP  = WI + 30256;
constexpr size_t I_KG_CUR = WI + 60256;
constexpr size_t I_KG_SL  = WI + 90256;
constexpr size_t I_C_RP   = WI + 290256;
constexpr size_t I_C_CUR  = WI + 320256;
constexpr size_t I_C_SL   = WI + 350256;
constexpr size_t I_TS_RP  = WI + 550256;
constexpr size_t I_TS_CUR = WI + 556256;
constexpr size_t I_TS_SL  = WI + 562256;
constexpr size_t I_IS_RP  = WI + 642256;
constexpr size_t I_IS_CUR = WI + 648256;
constexpr size_t I_IS_SL  = WI + 654256;       // ends int 734,256 = byte 9,228,480
constexpr size_t WS_PP2T_BYTE = 6291456;       // shorts offset 3,145,728
constexpr size_t WS_NEED      = 34603008;      // bytes for primary path

inline int cdiv(long a, long b) { return (int)((a + b - 1) / b); }

} // namespace

typedef short short8v __attribute__((ext_vector_type(8)));
typedef float f32x4 __attribute__((ext_vector_type(4)));

__device__ __forceinline__ unsigned short f2bf(float f) {
  union { float f; uint32_t u; } v; v.f = f;
  uint32_t u = v.u;
  u += 0x7fffu + ((u >> 16) & 1u);
  return (unsigned short)(u >> 16);
}
__device__ __forceinline__ uint32_t pkbf(float a, float b) {
  __hip_bfloat162 h = __float22bfloat162_rn(float2{a, b});
  union { __hip_bfloat162 h; uint32_t u; } cv; cv.h = h;
  return cv.u;
}
__device__ __forceinline__ float bflo(uint32_t u) {
  union { uint32_t u; float f; } c; c.u = u << 16; return c.f;
}
__device__ __forceinline__ float bfhi(uint32_t u) {
  union { uint32_t u; float f; } c; c.u = u & 0xFFFF0000u; return c.f;
}

__device__ __forceinline__ void gl16(const void* g, void* l) {
  __builtin_amdgcn_global_load_lds(
      (const __attribute__((address_space(1))) void*)g,
      (__attribute__((address_space(3))) void*)l, 16, 0, 0);
}

// ---------------------------------------------------------------------------
// conversion / utility kernels
// ---------------------------------------------------------------------------

__global__ void k_cvt(const float* __restrict__ x, unsigned short* __restrict__ o, size_t n2) {
  size_t i = (size_t)blockIdx.x * 256 + threadIdx.x;
  if (i >= n2) return;
  float2 v = *(const float2*)(x + 2 * i);
  *(uint32_t*)(o + 2 * i) = pkbf(v.x, v.y);
}

// f32 W[K][N] -> bf16 Wt[N][K]
__global__ void k_cvt_t(const float* __restrict__ W, unsigned short* __restrict__ Wt,
                        int K, int N) {
  __shared__ float t[32][33];
  int tx = threadIdx.x & 31, ty = threadIdx.x >> 5;
  int n0 = blockIdx.x * 32, k0 = blockIdx.y * 32;
#pragma unroll
  for (int j = 0; j < 4; ++j)
    t[ty + 8 * j][tx] = W[(size_t)(k0 + ty + 8 * j) * N + n0 + tx];
  __syncthreads();
#pragma unroll
  for (int j = 0; j < 4; ++j) {
    int n = ty + 8 * j;
    Wt[(size_t)(n0 + n) * K + k0 + tx] = f2bf(t[tx][n]);
  }
}

// wcat_t[(r*384+o)*384 + i] = sum_b comp[r][b]*bases[b][i][o]  (bf16)
__global__ void k_wcat(const float* __restrict__ comp, const float* __restrict__ bases,
                       unsigned short* __restrict__ Wt) {
  int idx = blockIdx.x * 256 + threadIdx.x;
  if (idx >= 12 * Dm * Dm) return;
  int i = idx % Dm;
  int o = (idx / Dm) % Dm;
  int r = idx / (Dm * Dm);
  float s = 0.f;
#pragma unroll
  for (int b = 0; b < 8; ++b)
    s += comp[r * 8 + b] * bases[(size_t)b * Dm * Dm + (size_t)i * Dm + o];
  Wt[idx] = f2bf(s);
}

__global__ void k_copy(float* __restrict__ d, const float* __restrict__ s, size_t n) {
  size_t i = (size_t)blockIdx.x * 256 + threadIdx.x;
  if (i < n) d[i] = s[i];
}

__global__ void k_scale_ip(float* __restrict__ d, float a, size_t n) {
  size_t i = (size_t)blockIdx.x * 256 + threadIdx.x;
  if (i < n) d[i] *= a;
}

__global__ void k_add2(float* __restrict__ o, const float* __restrict__ a,
                       const float* __restrict__ b, size_t n) {
  size_t i = (size_t)blockIdx.x * 256 + threadIdx.x;
  if (i < n) o[i] = a[i] + b[i];
}

__global__ void k_gather_f(const int* __restrict__ idx, const float* __restrict__ x,
                           float* __restrict__ out, int rows, int D) {
  size_t i = (size_t)blockIdx.x * 256 + threadIdx.x;
  if (i >= (size_t)rows * D) return;
  int r = (int)(i / D);
  int d = (int)(i - (size_t)r * D);
  out[i] = x[(size_t)idx[r] * D + d];
}

// gather bf16 rows as u32 chunks
__global__ void k_gather_b(const int* __restrict__ idx, const uint32_t* __restrict__ x2,
                           uint32_t* __restrict__ out2, int rows, int D2) {
  size_t i = (size_t)blockIdx.x * 256 + threadIdx.x;
  if (i >= (size_t)rows * D2) return;
  int r = (int)(i / D2);
  int c = (int)(i - (size_t)r * D2);
  out2[i] = x2[(size_t)idx[r] * D2 + c];
}

// ent[mte[m]][d] += 0.25*g[m][d]
__global__ void k_scatter_movie(const int* __restrict__ mte, const float* __restrict__ g,
                                float* __restrict__ ent) {
  size_t i = (size_t)blockIdx.x * 256 + threadIdx.x;
  if (i >= MBF) return;
  int m = (int)(i / Dm);
  int d = (int)(i - (size_t)m * Dm);
  atomicAdd(&ent[(size_t)mte[m] * Dm + d], 0.25f * g[i]);
}

// ---------------------------------------------------------------------------
// CSR build
// ---------------------------------------------------------------------------

__global__ void k_hist(const int* __restrict__ dst, int* __restrict__ cnt, int E) {
  int e = blockIdx.x * 256 + threadIdx.x;
  if (e < E) atomicAdd(&cnt[dst[e]], 1);
}

__global__ void k_scan_blk(const int* __restrict__ in, int* __restrict__ out,
                           int* __restrict__ part, int n) {
  __shared__ int s[256];
  int t = threadIdx.x;
  int g = blockIdx.x * 256 + t;
  int v = (g < n) ? in[g] : 0;
  s[t] = v;
  __syncthreads();
  for (int off = 1; off < 256; off <<= 1) {
    int add = (t >= off) ? s[t - off] : 0;
    __syncthreads();
    s[t] += add;
    __syncthreads();
  }
  if (g < n) out[g] = s[t] - v;
  if (t == 255) part[blockIdx.x] = s[255];
}

__global__ void k_scan_top(int* __restrict__ part, int nb) {
  __shared__ int s[256];
  int t = threadIdx.x;
  int v = (t < nb) ? part[t] : 0;
  s[t] = v;
  __syncthreads();
  for (int off = 1; off < 256; off <<= 1) {
    int add = (t >= off) ? s[t - off] : 0;
    __syncthreads();
    s[t] += add;
    __syncthreads();
  }
  if (t < nb) part[t] = s[t] - v;
}

__global__ void k_scan_add(int* __restrict__ out, const int* __restrict__ part, int n) {
  int g = blockIdx.x * 256 + threadIdx.x;
  if (g < n) out[g] += part[blockIdx.x];
}

__global__ void k_fill(const int* __restrict__ src, const int* __restrict__ dst,
                       const int* __restrict__ typ, int* __restrict__ cur,
                       int* __restrict__ slots, int E) {
  int e = blockIdx.x * 256 + threadIdx.x;
  if (e >= E) return;
  int d = dst[e];
  int pos = atomicAdd(&cur[d], 1);
  int v = src[e];
  if (typ) v |= (typ[e] << 16);   // src < 32768, typ < 16
  slots[pos] = v;
}

__global__ void k_dis_rp(const int* __restrict__ rp, float* __restrict__ dis, int n, int E) {
  int v = blockIdx.x * 256 + threadIdx.x;
  if (v >= n) return;
  int e0 = rp[v], e1 = (v + 1 < n) ? rp[v + 1] : E;
  dis[v] = rsqrtf((float)(e1 - e0) + 1.0f);
}

__global__ void k_count_type(const int* __restrict__ dst, const int* __restrict__ typ,
                             float* __restrict__ cnt, int E) {
  int i = blockIdx.x * 256 + threadIdx.x;
  if (i < E) atomicAdd(&cnt[(size_t)typ[i] * NE + dst[i]], 1.0f);
}

__global__ void k_rcp(float* __restrict__ c, size_t n) {
  size_t i = (size_t)blockIdx.x * 256 + threadIdx.x;
  if (i < n) { float v = c[i]; c[i] = (v > 0.f) ? 1.0f / v : 0.f; }
}

// ---------------------------------------------------------------------------
// gather kernels (no atomics): one wave per destination row
// ---------------------------------------------------------------------------

template <bool WRITE, bool ACC>
__global__ void k_gcn_g(const float* __restrict__ x, const float* __restrict__ dis,
                        const int* __restrict__ rp, const int* __restrict__ slots,
                        float* __restrict__ out, float* __restrict__ acc, int n, int E) {
  int v = (int)((blockIdx.x * (size_t)blockDim.x + threadIdx.x) >> 6);
  int lane = threadIdx.x & 63;
  if (v >= n) return;
  float dv = dis[v];
  const float* xr = x + (size_t)v * Dm;
  float a[6];
#pragma unroll
  for (int i = 0; i < 6; ++i) a[i] = dv * xr[lane + 64 * i];
  int e0 = rp[v], e1 = (v + 1 < n) ? rp[v + 1] : E;
  for (int e = e0; e < e1; ++e) {
    int s = slots[e];
    float c = dis[s];
    const float* xs = x + (size_t)s * Dm;
#pragma unroll
    for (int i = 0; i < 6; ++i) a[i] = fmaf(c, xs[lane + 64 * i], a[i]);
  }
#pragma unroll
  for (int i = 0; i < 6; ++i) a[i] *= dv;
  if (WRITE) {
    float* o = out + (size_t)v * Dm;
#pragma unroll
    for (int i = 0; i < 6; ++i) o[lane + 64 * i] = a[i];
  }
  if (ACC) {
    float* o = acc + (size_t)v * Dm;
#pragma unroll
    for (int i = 0; i < 6; ++i) o[lane + 64 * i] += a[i];
  }
}

// ent0[v] += sum_{e: rbase<=r<rbase+6} rcp[r][v] * hh[src][(r-rbase)*384 + c]
__global__ void k_rgcn_g(const unsigned short* __restrict__ hh, const float* __restrict__ rcp,
                         const int* __restrict__ rp, const int* __restrict__ slots,
                         float* __restrict__ ent0, int rbase, int E) {
  int v = (int)((blockIdx.x * (size_t)blockDim.x + threadIdx.x) >> 6);
  int lane = threadIdx.x & 63;
  if (v >= NE) return;
  int e0 = rp[v], e1 = (v + 1 < NE) ? rp[v + 1] : E;
  float* er = ent0 + (size_t)v * Dm;
  float2 a[3];
#pragma unroll
  for (int i = 0; i < 3; ++i) a[i] = *(const float2*)(er + 2 * lane + 128 * i);
  for (int e = e0; e < e1; ++e) {
    int p = slots[e];
    int r = p >> 16, s = p & 0xFFFF;
    if (r < rbase || r >= rbase + 6) continue;
    float nm = rcp[(size_t)r * NE + v];
    const unsigned short* hr = hh + (size_t)s * 2304 + (size_t)(r - rbase) * 384;
#pragma unroll
    for (int i = 0; i < 3; ++i) {
      uint32_t u = *(const uint32_t*)(hr + 2 * lane + 128 * i);
      a[i].x = fmaf(nm, bflo(u), a[i].x);
      a[i].y = fmaf(nm, bfhi(u), a[i].y);
    }
  }
#pragma unroll
  for (int i = 0; i < 3; ++i) *(float2*)(er + 2 * lane + 128 * i) = a[i];
}

// ---------------------------------------------------------------------------
// bf16 MFMA GEMM, m97 structure: 128x128 tile, BK=64, global_load_lds 16B,
// XOR-swizzled LDS via pre-swizzled global source. A[M][K], Wt[N][K] bf16.
// OUT: 0 = f32 C, 1 = bf16 C, 2 = f32 transposed prompt layout.
// ---------------------------------------------------------------------------
template <bool RELU, bool RES, int OUT>
__global__ __launch_bounds__(256) void mgemm_bf(
    const unsigned short* __restrict__ A, const unsigned short* __restrict__ Wt,
    const float* __restrict__ bias, const float* __restrict__ Rp,
    void* __restrict__ Cv, int M, int N, int K) {
  __shared__ __align__(16) unsigned short As[128 * 64];
  __shared__ __align__(16) unsigned short Bs[128 * 64];
  const int tid = threadIdx.x;
  const int lane = tid & 63;
  const int w = tid >> 6;
  const int bm = blockIdx.x * 128, bn = blockIdx.y * 128;
  const int wr = (w >> 1) * 64, wc = (w & 1) * 64;
  const int lrow = lane & 15, lq = lane >> 4;
  f32x4 acc[4][4] = {};

  const int prow_l = lane >> 3;
  const int pslot = lane & 7;

  for (int k0 = 0; k0 < K; k0 += 64) {
    __syncthreads();
#pragma unroll
    for (int j = 0; j < 4; ++j) {
      int seg = j * 4 + w;
      int prow = seg * 8 + prow_l;
      int aslot = pslot ^ (prow & 7);
      int arow = min(bm + prow, M - 1);
      gl16(A + (size_t)arow * K + k0 + aslot * 8, &As[seg * 512 + lane * 8]);
    }
#pragma unroll
    for (int j = 0; j < 4; ++j) {
      int seg = j * 4 + w;
      int prow = seg * 8 + prow_l;
      int bslot = pslot ^ (prow & 7);
      int brow = min(bn + prow, N - 1);
      gl16(Wt + (size_t)brow * K + k0 + bslot * 8, &Bs[seg * 512 + lane * 8]);
    }
    __syncthreads();
#pragma unroll
    for (int ks = 0; ks < 2; ++ks) {
      short8v af[4], bf[4];
      const int slot = ks * 4 + lq;
#pragma unroll
      for (int mr = 0; mr < 4; ++mr) {
        int r = wr + mr * 16 + lrow;
        af[mr] = *(const short8v*)&As[r * 64 + ((slot ^ (r & 7)) << 3)];
      }
#pragma unroll
      for (int nc = 0; nc < 4; ++nc) {
        int r = wc + nc * 16 + lrow;
        bf[nc] = *(const short8v*)&Bs[r * 64 + ((slot ^ (r & 7)) << 3)];
      }
#pragma unroll
      for (int mr = 0; mr < 4; ++mr)
#pragma unroll
        for (int nc = 0; nc < 4; ++nc)
          acc[mr][nc] = __builtin_amdgcn_mfma_f32_16x16x32_bf16(
              af[mr], bf[nc], acc[mr][nc], 0, 0, 0);
    }
  }
#pragma unroll
  for (int mr = 0; mr < 4; ++mr) {
#pragma unroll
    for (int e = 0; e < 4; ++e) {
      int r = bm + wr + mr * 16 + lq * 4 + e;
      if (r >= M) continue;
#pragma unroll
      for (int nc = 0; nc < 4; ++nc) {
        int c = bn + wc + nc * 16 + lrow;
        if (c >= N) continue;
        float v = acc[mr][nc][e];
        if (bias) v += bias[c];
        if (RES) v += Rp[(size_t)r * N + c];
        if (RELU) v = fmaxf(v, 0.f);
        if (OUT == 0) {
          ((float*)Cv)[(size_t)r * N + c] = v;
        } else if (OUT == 1) {
          ((unsigned short*)Cv)[(size_t)r * N + c] = f2bf(v);
        } else {
          int b = r >> 8, t = r & 255;
          int l = c / 1536, rem = c - l * 1536;
          int blk = rem / 768, rem2 = rem - blk * 768;
          int hh = rem2 >> 6, dd = rem2 & 63;
          size_t oi = (((((size_t)l * 2 + blk) * 16 + b) * 12 + hh) * 256 + t) * 64 + dd;
          ((float*)Cv)[oi] = v;
        }
      }
    }
  }
}

// Fallback FINAL GEMM (only if ws_size too small for pp2t): A bf16 via
// global_load_lds; W f32 [K][N] from d_in converted in-kernel.
__global__ __launch_bounds__(256) void mgemm_fin(
    const unsigned short* __restrict__ A, const float* __restrict__ W,
    const float* __restrict__ bias, float* __restrict__ O, int M, int N, int K) {
  __shared__ __align__(16) unsigned short As[128 * 64];
  __shared__ __align__(16) unsigned short Bs[128 * 64];
  const int tid = threadIdx.x;
  const int lane = tid & 63;
  const int w = tid >> 6;
  const int bm = blockIdx.x * 128, bn = blockIdx.y * 128;
  const int wr = (w >> 1) * 64, wc = (w & 1) * 64;
  const int lrow = lane & 15, lq = lane >> 4;
  f32x4 acc[4][4] = {};
  const int prow_l = lane >> 3;
  const int pslot = lane & 7;
  const int n_loc = tid & 127;
  const int kh = (tid >> 7) * 32;

  for (int k0 = 0; k0 < K; k0 += 64) {
    __syncthreads();
#pragma unroll
    for (int j = 0; j < 4; ++j) {
      int seg = j * 4 + w;
      int prow = seg * 8 + prow_l;
      int aslot = pslot ^ (prow & 7);
      gl16(A + (size_t)(bm + prow) * K + k0 + aslot * 8, &As[seg * 512 + lane * 8]);
    }
    float wv[32];
    const float* wp = W + (size_t)(k0 + kh) * N + bn + n_loc;
#pragma unroll
    for (int j = 0; j < 32; ++j) wv[j] = wp[(size_t)j * N];
#pragma unroll
    for (int c = 0; c < 4; ++c) {
      uint32_t u0 = pkbf(wv[8 * c + 0], wv[8 * c + 1]);
      uint32_t u1 = pkbf(wv[8 * c + 2], wv[8 * c + 3]);
      uint32_t u2 = pkbf(wv[8 * c + 4], wv[8 * c + 5]);
      uint32_t u3 = pkbf(wv[8 * c + 6], wv[8 * c + 7]);
      int s = (kh >> 3) + c;
      *(uint4*)&Bs[n_loc * 64 + ((s ^ (n_loc & 7)) << 3)] = uint4{u0, u1, u2, u3};
    }
    __syncthreads();
#pragma unroll
    for (int ks = 0; ks < 2; ++ks) {
      short8v af[4], bf[4];
      const int slot = ks * 4 + lq;
#pragma unroll
      for (int mr = 0; mr < 4; ++mr) {
        int r = wr + mr * 16 + lrow;
        af[mr] = *(const short8v*)&As[r * 64 + ((slot ^ (r & 7)) << 3)];
      }
#pragma unroll
      for (int nc = 0; nc < 4; ++nc) {
        int r = wc + nc * 16 + lrow;
        bf[nc] = *(const short8v*)&Bs[r * 64 + ((slot ^ (r & 7)) << 3)];
      }
#pragma unroll
      for (int mr = 0; mr < 4; ++mr)
#pragma unroll
        for (int nc = 0; nc < 4; ++nc)
          acc[mr][nc] = __builtin_amdgcn_mfma_f32_16x16x32_bf16(
              af[mr], bf[nc], acc[mr][nc], 0, 0, 0);
    }
  }
#pragma unroll
  for (int mr = 0; mr < 4; ++mr) {
#pragma unroll
    for (int e = 0; e < 4; ++e) {
      int r = bm + wr + mr * 16 + lq * 4 + e;
      int b = r >> 8, t = r & 255;
#pragma unroll
      for (int nc = 0; nc < 4; ++nc) {
        int c = bn + wc + nc * 16 + lrow;
        float v = acc[mr][nc][e] + bias[c];
        int l = c / 1536, rem = c - l * 1536;
        int blk = rem / 768, rem2 = rem - blk * 768;
        int hh = rem2 >> 6, dd = rem2 & 63;
        size_t oi = (((((size_t)l * 2 + blk) * 16 + b) * 12 + hh) * 256 + t) * 64 + dd;
        O[oi] = v;
      }
    }
  }
}

// ---------------------------------------------------------------------------
// fused cross-attention (bf16 inputs): one wave per (b,t)
// ---------------------------------------------------------------------------
__global__ __launch_bounds__(256) void k_attn(
    const unsigned short* __restrict__ qb, const unsigned short* __restrict__ eb_all,
    const unsigned short* __restrict__ tokb, float* __restrict__ pr0,
    unsigned short* __restrict__ pr0b) {
  int gw = (int)((blockIdx.x * (size_t)blockDim.x + threadIdx.x) >> 6);
  int lane = threadIdx.x & 63;
  if (gw >= NTOK) return;
  int b = gw >> 8;
  const unsigned short* qr = qb + (size_t)gw * Hm;
  float2 q[6];
#pragma unroll
  for (int i = 0; i < 6; ++i) {
    uint32_t u = *(const uint32_t*)(qr + 2 * lane + 128 * i);
    q[i] = float2{bflo(u), bfhi(u)};
  }
  const unsigned short* eb = eb_all + (size_t)b * LE * Hm;
  float myA = -3.0e38f;
  for (int e = 0; e < LE; ++e) {
    const unsigned short* er = eb + (size_t)e * Hm;
    float s = 0.f;
#pragma unroll
    for (int i = 0; i < 6; ++i) {
      uint32_t u = *(const uint32_t*)(er + 2 * lane + 128 * i);
      s = fmaf(q[i].x, bflo(u), s);
      s = fmaf(q[i].y, bfhi(u), s);
    }
#pragma unroll
    for (int off = 32; off > 0; off >>= 1) s += __shfl_xor(s, off);
    if (lane == e) myA = s * (1.0f / 768.0f);
  }
  float mx = myA;
#pragma unroll
  for (int off = 32; off > 0; off >>= 1) mx = fmaxf(mx, __shfl_xor(mx, off));
  float p = (lane < LE) ? expf(myA - mx) : 0.f;
  float sum = p;
#pragma unroll
  for (int off = 32; off > 0; off >>= 1) sum += __shfl_xor(sum, off);
  float wgt = p / sum;
  const unsigned short* tr = tokb + (size_t)gw * Hm;
  float2 a[6];
#pragma unroll
  for (int i = 0; i < 6; ++i) {
    uint32_t u = *(const uint32_t*)(tr + 2 * lane + 128 * i);
    a[i] = float2{bflo(u), bfhi(u)};
  }
  for (int e = 0; e < LE; ++e) {
    float we = __shfl(wgt, e);
    const unsigned short* er = eb + (size_t)e * Hm;
#pragma unroll
    for (int i = 0; i < 6; ++i) {
      uint32_t u = *(const uint32_t*)(er + 2 * lane + 128 * i);
      a[i].x = fmaf(we, bflo(u), a[i].x);
      a[i].y = fmaf(we, bfhi(u), a[i].y);
    }
  }
  float* orow = pr0 + (size_t)gw * Hm;
  unsigned short* obrow = pr0b + (size_t)gw * Hm;
#pragma unroll
  for (int i = 0; i < 6; ++i) {
    *(float2*)(orow + 2 * lane + 128 * i) = a[i];
    *(uint32_t*)(obrow + 2 * lane + 128 * i) = pkbf(a[i].x, a[i].y);
  }
}

// ---------------------------------------------------------------------------

extern "C" void kernel_launch(void* const* d_in, const int* in_sizes, int n_in,
                              void* d_out, int out_size, void* d_ws, size_t ws_size,
                              hipStream_t stream) {
  (void)in_sizes; (void)n_in; (void)out_size;

  const float* x_node = (const float*)d_in[0];
  const float* bases  = (const float*)d_in[1];
  const float* comp   = (const float*)d_in[2];
  const float* root   = (const float*)d_in[3];
  const float* rbias  = (const float*)d_in[4];
  const float* ep1w1  = (const float*)d_in[5];
  const float* ep1b1  = (const float*)d_in[6];
  const float* ep1w2  = (const float*)d_in[7];
  const float* ep1b2  = (const float*)d_in[8];
  const float* ep2w   = (const float*)d_in[9];
  const float* ep2b   = (const float*)d_in[10];
  const float* tp1w1  = (const float*)d_in[11];
  const float* tp1b1  = (const float*)d_in[12];
  const float* tp1w2  = (const float*)d_in[13];
  const float* tp1b2  = (const float*)d_in[14];
  const float* tp2w   = (const float*)d_in[15];
  const float* tp2b   = (const float*)d_in[16];
  const float* caw    = (const float*)d_in[17];
  const float* pp1w1  = (const float*)d_in[18];
  const float* pp1b1  = (const float*)d_in[19];
  const float* pp1w2  = (const float*)d_in[20];
  const float* pp1b2  = (const float*)d_in[21];
  const float* pp2w   = (const float*)d_in[22];
  const float* pp2b   = (const float*)d_in[23];
  const float* tokens = (const float*)d_in[24];
  const int* ei_kg = (const int*)d_in[25];
  const int* etype = (const int*)d_in[26];
  const int* ei_c  = (const int*)d_in[27];
  const int* ei_ts = (const int*)d_in[28];
  const int* ei_is = (const int*)d_in[29];
  const int* mte   = (const int*)d_in[30];
  const int* eids  = (const int*)d_in[31];

  float* O = (float*)d_out;
  unsigned short* xb    = (unsigned short*)(O + P_XB);
  unsigned short* wct   = (unsigned short*)(O + P_WCT);
  float* rcpc  = O + P_CNT;
  float* ent0  = O + P_ENT0;
  unsigned short* hh    = (unsigned short*)(O + P_HH);
  float* disc  = O + P_DIS;
  float* dist  = O + P_DIS + 30000;
  float* disi  = O + P_DIS + 36000;
  float* nf    = O + P_NF;
  float* g1    = O + P_G1;
  float* g2    = O + P_G2;
  float* g3    = O + P_G3;
  float* cprev = O + P_CPREV;
  float* ccur  = O + P_CCUR;
  float* accb  = O + P_ACC;
  unsigned short* entb  = (unsigned short*)(O + P_ENTB);
  unsigned short* hidb  = (unsigned short*)(O + P_HIDB);
  unsigned short* ent2b = (unsigned short*)(O + P_ENT2B);
  unsigned short* e768b = (unsigned short*)(O + P_E768B);
  unsigned short* tokb  = (unsigned short*)(O + P_TOKB);
  unsigned short* thidb = (unsigned short*)(O + P_THIDB);
  unsigned short* tok1b = (unsigned short*)(O + P_TOK1B);
  unsigned short* tok2b = (unsigned short*)(O + P_TOK2B);
  unsigned short* qb    = (unsigned short*)(O + P_QB);
  unsigned short* eemb  = (unsigned short*)(O + P_EEMB);
  float* pr0   = O + P_PR0;
  unsigned short* pr0b  = (unsigned short*)(O + P_PR0B);
  unsigned short* phidb = (unsigned short*)(O + P_PHIDB);
  unsigned short* wts   = (unsigned short*)(O + P_WT);

  int* iws = (int*)d_ws;
  unsigned short* p2b = (unsigned short*)d_ws;
  unsigned short* pp2t = (unsigned short*)d_ws + WS_PP2T_BYTE / 2;  // over dead CSR
  const bool ws_ok = (ws_size >= WS_NEED);
  int* cnt_i  = iws + I_CNT;
  int* part   = iws + I_PART;
  int* kg_rp  = iws + I_KG_RP;  int* kg_cur = iws + I_KG_CUR;  int* kg_sl = iws + I_KG_SL;
  int* c_rp   = iws + I_C_RP;   int* c_cur  = iws + I_C_CUR;   int* c_sl  = iws + I_C_SL;
  int* ts_rp  = iws + I_TS_RP;  int* ts_cur = iws + I_TS_CUR;  int* ts_sl = iws + I_TS_SL;
  int* is_rp  = iws + I_IS_RP;  int* is_cur = iws + I_IS_CUR;  int* is_sl = iws + I_IS_SL;

  const int EW = 256;

  // ---------------- phase A: conversions (NOT tokens, NOT pp2t) -----------
  k_cvt<<<cdiv(NBf / 2, EW), EW, 0, stream>>>(x_node, xb, NBf / 2);
  k_wcat<<<cdiv(12 * Dm * Dm, EW), EW, 0, stream>>>(comp, bases, wct);
  k_cvt_t<<<dim3(Dm / 32, Dm / 32), 256, 0, stream>>>(root, wts + S_ROOT, Dm, Dm);
  k_cvt_t<<<dim3(192 / 32, Dm / 32), 256, 0, stream>>>(ep1w1, wts + S_EP1A, Dm, 192);
  k_cvt_t<<<dim3(Dm / 32, 192 / 32), 256, 0, stream>>>(ep1w2, wts + S_EP1B, 192, Dm);
  k_cvt_t<<<dim3(Hm / 32, Dm / 32), 256, 0, stream>>>(ep2w, wts + S_EP2, Dm, Hm);
  k_cvt_t<<<dim3(Dm / 32, Hm / 32), 256, 0, stream>>>(tp1w1, wts + S_TP1A, Hm, Dm);
  k_cvt_t<<<dim3(Hm / 32, Dm / 32), 256, 0, stream>>>(tp1w2, wts + S_TP1B, Dm, Hm);
  k_cvt_t<<<dim3(Hm / 32, Hm / 32), 256, 0, stream>>>(tp2w, wts + S_TP2, Hm, Hm);
  k_cvt_t<<<dim3(Hm / 32, Hm / 32), 256, 0, stream>>>(caw, wts + S_CAW, Hm, Hm);
  k_cvt_t<<<dim3(Dm / 32, Hm / 32), 256, 0, stream>>>(pp1w1, wts + S_PP1A, Hm, Dm);
  k_cvt_t<<<dim3(Hm / 32, Dm / 32), 256, 0, stream>>>(pp1w2, wts + S_PP1B, Dm, Hm);

  // ---------------- CSR builds ----------------
  auto build_csr = [&](const int* ei, const int* typ, int n, int E,
                       int* rp, int* cur, int* sl) {
    hipMemsetAsync(cnt_i, 0, (size_t)n * 4, stream);
    k_hist<<<cdiv(E, EW), EW, 0, stream>>>(ei + E, cnt_i, E);
    int nb = cdiv(n, 256);
    k_scan_blk<<<nb, 256, 0, stream>>>(cnt_i, rp, part, n);
    k_scan_top<<<1, 256, 0, stream>>>(part, nb);
    k_scan_add<<<nb, 256, 0, stream>>>(rp, part, n);
    hipMemcpyAsync(cur, rp, (size_t)n * 4, hipMemcpyDeviceToDevice, stream);
    k_fill<<<cdiv(E, EW), EW, 0, stream>>>(ei, ei + E, typ, cur, sl, E);
  };
  build_csr(ei_kg, etype, NE, EKG, kg_rp, kg_cur, kg_sl);
  build_csr(ei_c, nullptr, NE, EC, c_rp, c_cur, c_sl);
  build_csr(ei_ts, nullptr, NM, ES, ts_rp, ts_cur, ts_sl);
  build_csr(ei_is, nullptr, NM, ES, is_rp, is_cur, is_sl);

  k_dis_rp<<<cdiv(NE, EW), EW, 0, stream>>>(c_rp, disc, NE, EC);
  k_dis_rp<<<cdiv(NM, EW), EW, 0, stream>>>(ts_rp, dist, NM, ES);
  k_dis_rp<<<cdiv(NM, EW), EW, 0, stream>>>(is_rp, disi, NM, ES);

  hipMemsetAsync(rcpc, 0, (size_t)12 * NE * 4, stream);
  k_count_type<<<cdiv(EKG, EW), EW, 0, stream>>>(ei_kg + EKG, etype, rcpc, EKG);
  k_rcp<<<cdiv((long)12 * NE, EW), EW, 0, stream>>>(rcpc, (size_t)12 * NE);

  // ---------------- RGCN ----------------
  mgemm_bf<false, true, 0><<<dim3(cdiv(NE, 128), cdiv(Dm, 128)), 256, 0, stream>>>(
      xb, wts + S_ROOT, rbias, x_node, ent0, NE, Dm, Dm);
  mgemm_bf<false, false, 1><<<dim3(cdiv(NE, 128), cdiv(6 * Dm, 128)), 256, 0, stream>>>(
      xb, wct, nullptr, nullptr, hh, NE, 6 * Dm, Dm);
  k_rgcn_g<<<cdiv((long)NE * 64, EW), EW, 0, stream>>>(hh, rcpc, kg_rp, kg_sl, ent0, 0, EKG);
  mgemm_bf<false, false, 1><<<dim3(cdiv(NE, 128), cdiv(6 * Dm, 128)), 256, 0, stream>>>(
      xb, wct + (size_t)6 * Dm * Dm, nullptr, nullptr, hh, NE, 6 * Dm, Dm);
  k_rgcn_g<<<cdiv((long)NE * 64, EW), EW, 0, stream>>>(hh, rcpc, kg_rp, kg_sl, ent0, 6, EKG);

  // ---------------- movie branch (gathers) ----------------
  k_gather_f<<<cdiv(MBF, EW), EW, 0, stream>>>(mte, ent0, nf, NM, Dm);
  k_gcn_g<true, false><<<cdiv((long)NM * 64, EW), EW, 0, stream>>>(
      nf, dist, ts_rp, ts_sl, g2, nullptr, NM, ES);
  k_gcn_g<true, false><<<cdiv((long)NM * 64, EW), EW, 0, stream>>>(
      g2, dist, ts_rp, ts_sl, g3, nullptr, NM, ES);
  k_add2<<<cdiv(MBF, EW), EW, 0, stream>>>(g1, g2, g3, MBF);
  k_gcn_g<true, true><<<cdiv((long)NM * 64, EW), EW, 0, stream>>>(
      nf, disi, is_rp, is_sl, g2, g1, NM, ES);
  k_gcn_g<false, true><<<cdiv((long)NM * 64, EW), EW, 0, stream>>>(
      g2, disi, is_rp, is_sl, nullptr, g1, NM, ES);

  // ---------------- entity GCN chain (last CSR use) ----------------
  k_copy<<<cdiv(NBf, EW), EW, 0, stream>>>(accb, ent0, NBf);
  k_gcn_g<true, true><<<cdiv((long)NE * 64, EW), EW, 0, stream>>>(
      ent0, disc, c_rp, c_sl, cprev, accb, NE, EC);
  k_gcn_g<true, true><<<cdiv((long)NE * 64, EW), EW, 0, stream>>>(
      cprev, disc, c_rp, c_sl, ccur, accb, NE, EC);
  k_gcn_g<false, true><<<cdiv((long)NE * 64, EW), EW, 0, stream>>>(
      ccur, disc, c_rp, c_sl, nullptr, accb, NE, EC);
  k_scale_ip<<<cdiv(NBf, EW), EW, 0, stream>>>(accb, 0.25f, NBf);
  k_scatter_movie<<<cdiv(MBF, EW), EW, 0, stream>>>(mte, g1, accb);
  k_cvt<<<cdiv(NBf / 2, EW), EW, 0, stream>>>(accb, entb, NBf / 2);

  // pp2t conversion: CSR arrays now dead; d_ws region free (primary path)
  if (ws_ok) {
    k_cvt_t<<<dim3(NO / 32, Hm / 32), 256, 0, stream>>>(pp2w, pp2t, Hm, NO);
  }

  // ---------------- entity MLP ----------------
  mgemm_bf<true, false, 1><<<dim3(cdiv(NE, 128), cdiv(192, 128)), 256, 0, stream>>>(
      entb, wts + S_EP1A, ep1b1, nullptr, hidb, NE, 192, Dm);
  mgemm_bf<false, true, 1><<<dim3(cdiv(NE, 128), cdiv(Dm, 128)), 256, 0, stream>>>(
      hidb, wts + S_EP1B, ep1b2, accb, ent2b, NE, Dm, 192);
  mgemm_bf<false, false, 1><<<dim3(cdiv(NE, 128), cdiv(Hm, 128)), 256, 0, stream>>>(
      ent2b, wts + S_EP2, ep2b, nullptr, e768b, NE, Hm, Dm);

  // ---------------- token path (tokb converted here; region now dead) -----
  k_cvt<<<cdiv((long)NTOK * Hm / 2, EW), EW, 0, stream>>>(tokens, tokb, (size_t)NTOK * Hm / 2);
  mgemm_bf<true, false, 1><<<dim3(cdiv(NTOK, 128), cdiv(Dm, 128)), 256, 0, stream>>>(
      tokb, wts + S_TP1A, tp1b1, nullptr, thidb, NTOK, Dm, Hm);
  mgemm_bf<false, true, 1><<<dim3(cdiv(NTOK, 128), cdiv(Hm, 128)), 256, 0, stream>>>(
      thidb, wts + S_TP1B, tp1b2, tokens, tok1b, NTOK, Hm, Dm);
  mgemm_bf<false, false, 1><<<dim3(cdiv(NTOK, 128), cdiv(Hm, 128)), 256, 0, stream>>>(
      tok1b, wts + S_TP2, tp2b, nullptr, tok2b, NTOK, Hm, Hm);
  mgemm_bf<false, false, 1><<<dim3(cdiv(NTOK, 128), cdiv(Hm, 128)), 256, 0, stream>>>(
      tok2b, wts + S_CAW, nullptr, nullptr, qb, NTOK, Hm, Hm);

  k_gather_b<<<cdiv((long)Bc * LE * (Hm / 2), EW), EW, 0, stream>>>(
      eids, (const uint32_t*)e768b, (uint32_t*)eemb, Bc * LE, Hm / 2);
  k_attn<<<cdiv((long)NTOK * 64, 256), 256, 0, stream>>>(qb, eemb, tok2b, pr0, pr0b);

  mgemm_bf<true, false, 1><<<dim3(cdiv(NTOK, 128), cdiv(Dm, 128)), 256, 0, stream>>>(
      pr0b, wts + S_PP1A, pp1b1, nullptr, phidb, NTOK, Dm, Hm);
  mgemm_bf<false, true, 1><<<dim3(cdiv(NTOK, 128), cdiv(Hm, 128)), 256, 0, stream>>>(
      phidb, wts + S_PP1B, pp1b2, pr0, p2b, NTOK, Hm, Dm);

  // ---------------- final GEMM + transpose (reads ONLY d_ws/d_in) ---------
  if (ws_ok) {
    mgemm_bf<false, false, 2><<<dim3(NTOK / 128, NO / 128), 256, 0, stream>>>(
        p2b, pp2t, pp2b, nullptr, O, NTOK, NO, Hm);
  } else {
    mgemm_fin<<<dim3(NTOK / 128, NO / 128), 256, 0, stream>>>(
        p2b, pp2w, pp2b, O, NTOK, NO, Hm);
  }
}